// Round 3
// baseline (314.224 us; speedup 1.0000x reference)
//
#include <hip/hip_runtime.h>

// Problem constants (B,T,D,U) = (64, 2048, 256, 256)
#define B 64
#define T 2048
#define D 256
#define U 256
#define NC 32          // t-chunks per batch (grid = B*NC = 2048 blocks -> full occupancy)
#define TC (T / NC)    // 64 rows per chunk

// ws layout (floats):
//   [0,256)        wv = W @ v
//   [256,320)      per-batch arrival counters (int, zeroed by k_wv)
//   [320, +B*NC)   chunk max m_c
//   [.., +B*NC)    chunk sum l_c
//   [.., +B*NC*D)  chunk weighted accum O_c
#define WS_WV   0
#define WS_CNT  (WS_WV + 256)
#define WS_M    (WS_CNT + B)
#define WS_L    (WS_M + B * NC)
#define WS_O    (WS_L + B * NC)

// ------------------------------------------- wv = W @ v ; zero counters
__global__ __launch_bounds__(256) void k_wv(const float* __restrict__ W,
                                            const float* __restrict__ v,
                                            float* __restrict__ wv,
                                            int* __restrict__ cnt) {
    int d = threadIdx.x;
    if (d < B) cnt[d] = 0;
    const float4* Wr = (const float4*)(W + d * U);
    const float4* v4 = (const float4*)v;
    float acc = 0.f;
    #pragma unroll 4
    for (int u = 0; u < U / 4; ++u) {
        float4 w = Wr[u];
        float4 vv = v4[u];
        acc += w.x * vv.x + w.y * vv.y + w.z * vv.z + w.w * vv.w;
    }
    wv[d] = acc;
}

// ---- fused: scores + online softmax + weighted accum + last-block combine
// Block = (b, c). 4 waves; wave q handles rows t = q, q+4, ... of the chunk.
// x is read ONCE; flash-style running (m, l, acc) per wave; chunk partials
// merged across waves in LDS; the last-arriving block per batch (device-scope
// atomic counter) performs the final cross-chunk normalization.
__global__ __launch_bounds__(256) void k_fused(const float* __restrict__ x,
                                               const float* __restrict__ wv,
                                               float* __restrict__ pM,
                                               float* __restrict__ pL,
                                               float* __restrict__ pO,
                                               int* __restrict__ cnt,
                                               float* __restrict__ out) {
    int b = blockIdx.x >> 5;          // NC == 32
    int c = blockIdx.x & (NC - 1);
    int l = threadIdx.x & 63;
    int q = threadIdx.x >> 6;         // wave-uniform

    float4 w4 = ((const float4*)wv)[l];
    const float4* xb =
        (const float4*)(x + ((long long)b * T + (long long)c * TC) * D);

    float m = -1e30f, lsum = 0.f;
    float4 acc = {0.f, 0.f, 0.f, 0.f};

    #pragma unroll 4
    for (int t = q; t < TC; t += 4) {
        float4 xv = xb[(long long)t * 64 + l];   // coalesced 1 KB per wave
        float s = xv.x * w4.x + xv.y * w4.y + xv.z * w4.z + xv.w * w4.w;
        #pragma unroll
        for (int off = 1; off < 64; off <<= 1)   // butterfly: all lanes get sum
            s += __shfl_xor(s, off, 64);
        float m_new = fmaxf(m, s);
        float alpha = __expf(m - m_new);         // exp(-inf)=0 handles first iter
        float p = __expf(s - m_new);
        lsum = lsum * alpha + p;
        acc.x = fmaf(p, xv.x, acc.x * alpha);
        acc.y = fmaf(p, xv.y, acc.y * alpha);
        acc.z = fmaf(p, xv.z, acc.z * alpha);
        acc.w = fmaf(p, xv.w, acc.w * alpha);
        m = m_new;
    }

    // cross-wave combine via LDS
    __shared__ float4 redO[4][64];
    __shared__ float redM[4], redL[4];
    __shared__ int isLast;
    redO[q][l] = acc;
    if (l == 0) { redM[q] = m; redL[q] = lsum; }
    __syncthreads();
    if (q == 0) {
        float M = fmaxf(fmaxf(redM[0], redM[1]), fmaxf(redM[2], redM[3]));
        float e0 = __expf(redM[0] - M), e1 = __expf(redM[1] - M);
        float e2 = __expf(redM[2] - M), e3 = __expf(redM[3] - M);
        float4 a0 = redO[0][l], a1 = redO[1][l], a2 = redO[2][l], a3 = redO[3][l];
        float4 r;
        r.x = a0.x * e0 + a1.x * e1 + a2.x * e2 + a3.x * e3;
        r.y = a0.y * e0 + a1.y * e1 + a2.y * e2 + a3.y * e3;
        r.z = a0.z * e0 + a1.z * e1 + a2.z * e2 + a3.z * e3;
        r.w = a0.w * e0 + a1.w * e1 + a2.w * e2 + a3.w * e3;
        ((float4*)(pO + (long long)blockIdx.x * D))[l] = r;
        if (l == 0) {
            pM[blockIdx.x] = M;
            pL[blockIdx.x] = redL[0] * e0 + redL[1] * e1 + redL[2] * e2 + redL[3] * e3;
        }
    }
    // last-block-per-batch election (device-scope atomics; fences for
    // cross-XCD visibility of the partials written above)
    if (threadIdx.x == 0) {
        __threadfence();
        int old = atomicAdd(&cnt[b], 1);
        isLast = (old == NC - 1);
    }
    __syncthreads();
    if (isLast) {
        __threadfence();
        int d = threadIdx.x;
        volatile const float* vM = pM + b * NC;
        volatile const float* vL = pL + b * NC;
        volatile const float* vO = pO + (long long)b * NC * D;
        float M = -1e30f;
        #pragma unroll
        for (int k = 0; k < NC; ++k)
            M = fmaxf(M, vM[k]);
        float denom = 0.f, a = 0.f;
        #pragma unroll
        for (int k = 0; k < NC; ++k) {
            float e = __expf(vM[k] - M);
            denom += e * vL[k];
            a = fmaf(e, vO[(long long)k * D + d], a);
        }
        out[(long long)b * D + d] = a / denom;
    }
}

extern "C" void kernel_launch(void* const* d_in, const int* in_sizes, int n_in,
                              void* d_out, int out_size, void* d_ws, size_t ws_size,
                              hipStream_t stream) {
    // inputs: x, g, W, Wg, b, v  -- g/Wg/b cancel under softmax shift-invariance
    const float* x = (const float*)d_in[0];
    const float* W = (const float*)d_in[2];
    const float* v = (const float*)d_in[5];
    float* ws = (float*)d_ws;
    float* wv = ws + WS_WV;
    int*   cnt = (int*)(ws + WS_CNT);
    float* pM = ws + WS_M;
    float* pL = ws + WS_L;
    float* pO = ws + WS_O;
    float* out = (float*)d_out;

    k_wv<<<1, 256, 0, stream>>>(W, v, wv, cnt);
    k_fused<<<B * NC, 256, 0, stream>>>(x, wv, pM, pL, pO, cnt, out);
}

// Round 4
// 216.506 us; speedup vs baseline: 1.4513x; 1.4513x over previous
//
#include <hip/hip_runtime.h>

// Problem constants (B,T,D,U) = (64, 2048, 256, 256)
#define B 64
#define T 2048
#define D 256
#define U 256
#define NC 32          // t-chunks per batch (grid = B*NC = 2048 blocks)
#define TC (T / NC)    // 64 rows per chunk; 16 rows per wave
#define RPW 16         // rows per wave (TC / 4 waves)

// ws layout (floats):
//   [0,256)        wv = W @ v
//   [256, +B*NC)   chunk max m_c
//   [.., +B*NC)    chunk sum l_c
//   [.., +B*NC*D)  chunk weighted accum O_c
#define WS_WV   0
#define WS_M    (WS_WV + 256)
#define WS_L    (WS_M + B * NC)
#define WS_O    (WS_L + B * NC)

// ---------------------------------------------------------------- wv = W @ v
__global__ __launch_bounds__(256) void k_wv(const float* __restrict__ W,
                                            const float* __restrict__ v,
                                            float* __restrict__ wv) {
    int d = threadIdx.x;
    const float4* Wr = (const float4*)(W + d * U);
    const float4* v4 = (const float4*)v;
    float acc = 0.f;
    #pragma unroll 4
    for (int u = 0; u < U / 4; ++u) {
        float4 w = Wr[u];
        float4 vv = v4[u];
        acc += w.x * vv.x + w.y * vv.y + w.z * vv.z + w.w * vv.w;
    }
    wv[d] = acc;
}

// ---- fused: scores + chunk softmax partials + weighted accum, 1 pass over x
// Block = (b, c). 4 waves; wave q handles rows t = q*16 .. q*16+15.
// All 16 x-rows are held in VGPRs: the 16 score reductions are INDEPENDENT
// (no online-softmax serial chain), then one exp pass reuses the registers
// for the weighted accumulation. No fences/atomics — the combine kernel
// boundary provides cross-block ordering (single-kernel last-block combine
// regressed 7x in R3: device-scope fences flush per-XCD L2 on gfx950).
__global__ __launch_bounds__(256) void k_fused(const float* __restrict__ x,
                                               const float* __restrict__ wv,
                                               float* __restrict__ pM,
                                               float* __restrict__ pL,
                                               float* __restrict__ pO) {
    int b = blockIdx.x >> 5;          // NC == 32
    int c = blockIdx.x & (NC - 1);
    int l = threadIdx.x & 63;
    int q = threadIdx.x >> 6;         // wave-uniform

    float4 w4 = ((const float4*)wv)[l];
    const float4* xb =
        (const float4*)(x + ((long long)b * T + (long long)c * TC) * D);

    float4 xv[RPW];
    float  s[RPW];
    #pragma unroll
    for (int i = 0; i < RPW; ++i)               // 16 outstanding 16B loads
        xv[i] = xb[(q * RPW + i) * 64 + l];

    #pragma unroll
    for (int i = 0; i < RPW; ++i) {             // independent reductions -> ILP
        float t = xv[i].x * w4.x + xv[i].y * w4.y + xv[i].z * w4.z + xv[i].w * w4.w;
        #pragma unroll
        for (int off = 1; off < 64; off <<= 1)
            t += __shfl_xor(t, off, 64);
        s[i] = t;
    }

    float m = s[0];
    #pragma unroll
    for (int i = 1; i < RPW; ++i) m = fmaxf(m, s[i]);

    float lsum = 0.f;
    float4 acc = {0.f, 0.f, 0.f, 0.f};
    #pragma unroll
    for (int i = 0; i < RPW; ++i) {
        float p = __expf(s[i] - m);
        lsum += p;
        acc.x = fmaf(p, xv[i].x, acc.x);
        acc.y = fmaf(p, xv[i].y, acc.y);
        acc.z = fmaf(p, xv[i].z, acc.z);
        acc.w = fmaf(p, xv[i].w, acc.w);
    }

    // cross-wave combine via LDS
    __shared__ float4 redO[4][64];
    __shared__ float redM[4], redL[4];
    redO[q][l] = acc;
    if (l == 0) { redM[q] = m; redL[q] = lsum; }
    __syncthreads();
    if (q == 0) {
        float M = fmaxf(fmaxf(redM[0], redM[1]), fmaxf(redM[2], redM[3]));
        float e0 = __expf(redM[0] - M), e1 = __expf(redM[1] - M);
        float e2 = __expf(redM[2] - M), e3 = __expf(redM[3] - M);
        float4 a0 = redO[0][l], a1 = redO[1][l], a2 = redO[2][l], a3 = redO[3][l];
        float4 r;
        r.x = a0.x * e0 + a1.x * e1 + a2.x * e2 + a3.x * e3;
        r.y = a0.y * e0 + a1.y * e1 + a2.y * e2 + a3.y * e3;
        r.z = a0.z * e0 + a1.z * e1 + a2.z * e2 + a3.z * e3;
        r.w = a0.w * e0 + a1.w * e1 + a2.w * e2 + a3.w * e3;
        ((float4*)(pO + (long long)blockIdx.x * D))[l] = r;
        if (l == 0) {
            pM[blockIdx.x] = M;
            pL[blockIdx.x] = redL[0] * e0 + redL[1] * e1 + redL[2] * e2 + redL[3] * e3;
        }
    }
}

// ---------------- combine NC chunk-partials per batch -> out[b,:]
__global__ __launch_bounds__(256) void k_combine(const float* __restrict__ pM,
                                                 const float* __restrict__ pL,
                                                 const float* __restrict__ pO,
                                                 float* __restrict__ out) {
    int b = blockIdx.x;
    int d = threadIdx.x;
    float M = -1e30f;
    #pragma unroll
    for (int c = 0; c < NC; ++c)
        M = fmaxf(M, pM[b * NC + c]);
    float denom = 0.f, acc = 0.f;
    #pragma unroll
    for (int c = 0; c < NC; ++c) {
        float e = __expf(pM[b * NC + c] - M);
        denom += e * pL[b * NC + c];
        acc = fmaf(e, pO[((long long)(b * NC + c)) * D + d], acc);
    }
    out[(long long)b * D + d] = acc / denom;
}

extern "C" void kernel_launch(void* const* d_in, const int* in_sizes, int n_in,
                              void* d_out, int out_size, void* d_ws, size_t ws_size,
                              hipStream_t stream) {
    // inputs: x, g, W, Wg, b, v  -- g/Wg/b cancel under softmax shift-invariance
    const float* x = (const float*)d_in[0];
    const float* W = (const float*)d_in[2];
    const float* v = (const float*)d_in[5];
    float* ws = (float*)d_ws;
    float* wv = ws + WS_WV;
    float* pM = ws + WS_M;
    float* pL = ws + WS_L;
    float* pO = ws + WS_O;
    float* out = (float*)d_out;

    k_wv<<<1, 256, 0, stream>>>(W, v, wv);
    k_fused<<<B * NC, 256, 0, stream>>>(x, wv, pM, pL, pO);
    k_combine<<<B, 256, 0, stream>>>(pM, pL, pO, out);
}